// Round 8
// baseline (58.117 us; speedup 1.0000x reference)
//
#include <hip/hip_runtime.h>
#include <math.h>

#define NNV 4096   // N
#define KKV 64     // K
#define BBV 256    // B
#define CHN 256    // n-chunk staged in LDS
#define NCH (NNV / CHN)

typedef unsigned short u16;
typedef unsigned int u32;
typedef u32  u32x4  __attribute__((ext_vector_type(4)));
typedef short bf16x8 __attribute__((ext_vector_type(8)));
typedef float f32x4  __attribute__((ext_vector_type(4)));
typedef float f32x16 __attribute__((ext_vector_type(16)));

__device__ inline u16 f2bf(float x) {           // RNE f32 -> bf16
    u32 u = __float_as_uint(x);
    u = u + 0x7FFFu + ((u >> 16) & 1u);
    return (u16)(u >> 16);
}

__device__ inline float rlane(float v, int l) { // wave-uniform readlane broadcast
    return __uint_as_float(__builtin_amdgcn_readlane(__float_as_uint(v), l));
}

// ================= K1: elementwise prep (+ Cs build in blocks 256..319) ===========
__global__ __launch_bounds__(256) void prep(
    const float* __restrict__ targets, const float* __restrict__ rho,
    const float* __restrict__ qs, const float* __restrict__ means,
    const float* __restrict__ C, const float* __restrict__ psi,
    u16* __restrict__ Csbf, u16* __restrict__ dsbf,
    u32* __restrict__ mask2, float* __restrict__ scal) {
    const int blk = blockIdx.x;
    const int t = threadIdx.x;

    if (blk >= BBV) {                    // Cs = C * rsqrt(psi), bf16, row-major [64][4096]
        const int k = blk - BBV;
        const float* Crow = C + (size_t)k * NNV;
        u16* Orow = Csbf + (size_t)k * NNV;
        const int base = t * 16;
#pragma unroll
        for (int j = 0; j < 16; j += 4) {
            float4 cv = *(const float4*)(Crow + base + j);
            float4 pv = *(const float4*)(psi + base + j);
            u32 w0 = (u32)f2bf(cv.x * rsqrtf(pv.x)) | ((u32)f2bf(cv.y * rsqrtf(pv.y)) << 16);
            u32 w1 = (u32)f2bf(cv.z * rsqrtf(pv.z)) | ((u32)f2bf(cv.w * rsqrtf(pv.w)) << 16);
            *(uint2*)(Orow + base + j) = make_uint2(w0, w1);
        }
        return;
    }

    __shared__ float sred[4][5];
    const int b = blk;
    const int lane = t & 63, wid = t >> 6;
    const float rho_s = rho[0];
    const float lrho = __logf(rho_s);
    const int base = t * 16;
    const float* tg = targets + (size_t)b * NNV + base;
    const float* qb = qs + (size_t)b * NNV + base;
    const float* mb = means + (size_t)b * NNV + base;
    const float* pb = psi + base;

    float tvv[16], qv[16], muv[16], pv[16];
#pragma unroll
    for (int j = 0; j < 16; j += 4) {
        *(float4*)(tvv + j) = *(const float4*)(tg + j);
        *(float4*)(qv + j)  = *(const float4*)(qb + j);
        *(float4*)(muv + j) = *(const float4*)(mb + j);
        *(float4*)(pv + j)  = *(const float4*)(pb + j);
    }

    float s_uni = 0.f, s_wdd = 0.f, s_nb = 0.f, s_mlp = 0.f, s_extra = 0.f;
    u16 dsv[16]; bool mk[16];
#pragma unroll
    for (int j = 0; j < 16; ++j) {
        bool m = tvv[j] >= rho_s;
        float ds = 0.f;
        if (m) {
            float y = __logf(tvv[j]);
            float d = y - muv[j];
            ds = d * rsqrtf(pv[j]);               // ds^2 = w*d^2
            s_wdd += ds * ds;
            s_nb += 1.f;
            s_mlp += __logf(pv[j]);
            s_extra += __logf(qv[j]) - y;
        } else {
            s_uni += __logf(1.f - qv[j]) - lrho;
        }
        dsv[j] = f2bf(ds);
        mk[j] = m;
    }
    u32 mw[8], dp[8];
#pragma unroll
    for (int i = 0; i < 8; ++i) {
        mw[i] = (mk[2*i] ? 0xFFFFu : 0u) | (mk[2*i+1] ? 0xFFFF0000u : 0u);
        dp[i] = (u32)dsv[2*i] | ((u32)dsv[2*i+1] << 16);
    }
    *(u32x4*)(dsbf + (size_t)b * NNV + base)     = ((u32x4*)dp)[0];
    *(u32x4*)(dsbf + (size_t)b * NNV + base + 8) = ((u32x4*)dp)[1];
    *(u32x4*)(mask2 + (size_t)b * (NNV/2) + t*8)     = ((u32x4*)mw)[0];
    *(u32x4*)(mask2 + (size_t)b * (NNV/2) + t*8 + 4) = ((u32x4*)mw)[1];

#pragma unroll
    for (int off = 32; off > 0; off >>= 1) {
        s_uni  += __shfl_down(s_uni, off);
        s_wdd  += __shfl_down(s_wdd, off);
        s_nb   += __shfl_down(s_nb, off);
        s_mlp  += __shfl_down(s_mlp, off);
        s_extra+= __shfl_down(s_extra, off);
    }
    if (lane == 0) {
        sred[wid][0] = s_uni; sred[wid][1] = s_wdd; sred[wid][2] = s_nb;
        sred[wid][3] = s_mlp; sred[wid][4] = s_extra;
    }
    __syncthreads();
    if (t == 0) {
        float a0=0,a1=0,a2=0,a3=0,a4=0;
#pragma unroll
        for (int w4 = 0; w4 < 4; ++w4) {
            a0 += sred[w4][0]; a1 += sred[w4][1]; a2 += sred[w4][2];
            a3 += sred[w4][3]; a4 += sred[w4][4];
        }
        scal[b*5+0]=a0; scal[b*5+1]=a1; scal[b*5+2]=a2; scal[b*5+3]=a3; scal[b*5+4]=a4;
    }
}

// ========== K2: Gram via MFMA — 2 batches/block share Cs reads, n-split in 2 ==========
// Block (pair,nhalf) processes batches {2*pair, 2*pair+1} over n in [nhalf*2048, ...+2048).
// Writes partial A, u; chol64 sums the two n-half partials.
__global__ __launch_bounds__(512, 2) void gram(
    const u16* __restrict__ Csbf, const u16* __restrict__ dsbf,
    const u32* __restrict__ mask2g, float* __restrict__ Apart, float* __restrict__ Upart) {
    __shared__ __align__(16) u16 gbuf[3][KKV * CHN];   // swizzled Cs chunk, 32 KB each
    __shared__ __align__(16) u16 dsrow[2][3][512];     // per-batch ds rows (upper 512B dup)
    __shared__ __align__(16) u32 m2[2][NNV / 2];       // per-batch packed masks, 8 KB each

    const int bid = blockIdx.x;
    const int nhalf = bid & 1;
    const int pair = bid >> 1;
    const int b0 = pair * 2, b1 = b0 + 1;
    const int c0 = nhalf * (NCH / 2);    // first chunk of this block's n-range

    const int t = threadIdx.x;
    const int lane = t & 63;
    const int w = t >> 6;
    const int half = w & 1;
    const int tilid = w >> 1;          // 0,1,2 = A00,A10,A11 ; 3 = u-waves
    const int l31 = lane & 31;
    const int hsel = lane >> 5;

    {   // stage both batches' mask words (full 8 KB each; only our half is read)
        u32x4 v0 = *(const u32x4*)(mask2g + (size_t)b0 * (NNV/2) + t*4);
        *(u32x4*)(&m2[0][t*4]) = v0;
        u32x4 v1 = *(const u32x4*)(mask2g + (size_t)b1 * (NNV/2) + t*4);
        *(u32x4*)(&m2[1][t*4]) = v1;
    }

    f32x16 acc0, acc1;
#pragma unroll
    for (int i = 0; i < 16; ++i) { acc0[i] = 0.f; acc1[i] = 0.f; }
    f32x4 ua0, ub0, ua1, ub1;
#pragma unroll
    for (int i = 0; i < 4; ++i) { ua0[i] = 0.f; ub0[i] = 0.f; ua1[i] = 0.f; ub1[i] = 0.f; }

// Every wave issues exactly 6 global_load_lds per STAGE (4 Cs rows + 2 ds-rows;
// ds-rows written identically by all 8 waves -> benign, keeps vmcnt uniform).
#define STAGE(cc, pp) do {                                                          \
    _Pragma("unroll")                                                               \
    for (int i_ = 0; i_ < 4; ++i_) {                                                \
        int beta0 = w*256 + i_*64;                                                  \
        int beta = beta0 + lane;                                                    \
        int r_ = beta >> 5, blkP = beta & 31;                                       \
        int blkS = blkP ^ (r_ & 15);   /* source pre-swizzle (m173 pattern) */      \
        const u16* src = Csbf + (size_t)r_ * NNV + (cc)*CHN + blkS*8;               \
        __builtin_amdgcn_global_load_lds(                                           \
            (const __attribute__((address_space(1))) void*)src,                     \
            (__attribute__((address_space(3))) void*)(&gbuf[pp][beta0*8]),          \
            16, 0, 0);                                                              \
    }                                                                               \
    {                                                                               \
        const u16* s0_ = dsbf + (size_t)b0 * NNV + (cc)*CHN + (lane & 31)*8;        \
        __builtin_amdgcn_global_load_lds(                                           \
            (const __attribute__((address_space(1))) void*)s0_,                     \
            (__attribute__((address_space(3))) void*)(&dsrow[0][pp][0]),            \
            16, 0, 0);                                                              \
        const u16* s1_ = dsbf + (size_t)b1 * NNV + (cc)*CHN + (lane & 31)*8;        \
        __builtin_amdgcn_global_load_lds(                                           \
            (const __attribute__((address_space(1))) void*)s1_,                     \
            (__attribute__((address_space(3))) void*)(&dsrow[1][pp][0]),            \
            16, 0, 0);                                                              \
    }                                                                               \
} while (0)

    STAGE(c0 + 0, 0);
    STAGE(c0 + 1, 1);
    // wait stage-0 complete (stage-1's 6 loads may remain in flight) + m2 writes
    asm volatile("s_waitcnt vmcnt(6) lgkmcnt(0)" ::: "memory");
    __builtin_amdgcn_s_barrier();

#pragma unroll
    for (int cl = 0; cl < NCH / 2; ++cl) {
        const int c = c0 + cl;
        const int p = cl % 3;
        if (cl + 2 < NCH / 2) STAGE(c0 + cl + 2, (cl + 2) % 3);
        const char* gb = (const char*)gbuf[p];
        if (w < 6) {
            const int rbA = (tilid == 0) ? 0 : 32;
            const int rbB = (tilid == 2) ? 32 : 0;
            const int rA = rbA + l31, rB = rbB + l31;
            const int swA = (rA & 15) << 4, swB = (rB & 15) << 4;
            const char* mb0 = (const char*)&m2[0][0] + c*512 + hsel*16;
            const char* mb1 = (const char*)&m2[1][0] + c*512 + hsel*16;
#pragma unroll
            for (int s8 = 0; s8 < 8; ++s8) {
                const int s = half*8 + s8;
                const int colbyte = s*32 + hsel*16;
                u32x4 fB = *(const u32x4*)(gb + rB*512 + (colbyte ^ swB));
                u32x4 fAr;
                if (tilid == 1) fAr = *(const u32x4*)(gb + rA*512 + (colbyte ^ swA));
                else            fAr = fB;                      // diag tiles: reuse read
                u32x4 mk0 = *(const u32x4*)(mb0 + s*32);       // broadcast per half-wave
                u32x4 mk1 = *(const u32x4*)(mb1 + s*32);
                u32x4 fA0 = fAr & mk0;                         // mask A-side only (m^2=m)
                u32x4 fA1 = fAr & mk1;
                acc0 = __builtin_amdgcn_mfma_f32_32x32x16_bf16(
                        __builtin_bit_cast(bf16x8, fA0),
                        __builtin_bit_cast(bf16x8, fB), acc0, 0, 0, 0);
                acc1 = __builtin_amdgcn_mfma_f32_32x32x16_bf16(
                        __builtin_bit_cast(bf16x8, fA1),
                        __builtin_bit_cast(bf16x8, fB), acc1, 0, 0, 0);
            }
        } else {
            const int cb0 = (w == 6) ? 0 : 32;
            const int l15 = lane & 15;
            const int g4 = lane >> 4;
            const int r0 = cb0 + l15, r1 = r0 + 16;
            const int sw0 = (r0 & 15) << 4, sw1 = (r1 & 15) << 4;
            const char* dr0 = (const char*)&dsrow[0][p][0];
            const char* dr1 = (const char*)&dsrow[1][p][0];
#pragma unroll
            for (int su = 0; su < 8; ++su) {
                const int colbyte = su*64 + g4*16;
                u32x4 dv0 = *(const u32x4*)(dr0 + colbyte);    // broadcast
                u32x4 dv1 = *(const u32x4*)(dr1 + colbyte);
                if (l15 != 0) { dv0 = dv0 ^ dv0; dv1 = dv1 ^ dv1; }  // A rows 1..15 = 0
                u32x4 f0 = *(const u32x4*)(gb + r0*512 + (colbyte ^ sw0));
                u32x4 f1 = *(const u32x4*)(gb + r1*512 + (colbyte ^ sw1));
                ua0 = __builtin_amdgcn_mfma_f32_16x16x32_bf16(
                        __builtin_bit_cast(bf16x8, dv0), __builtin_bit_cast(bf16x8, f0), ua0, 0,0,0);
                ub0 = __builtin_amdgcn_mfma_f32_16x16x32_bf16(
                        __builtin_bit_cast(bf16x8, dv0), __builtin_bit_cast(bf16x8, f1), ub0, 0,0,0);
                ua1 = __builtin_amdgcn_mfma_f32_16x16x32_bf16(
                        __builtin_bit_cast(bf16x8, dv1), __builtin_bit_cast(bf16x8, f0), ua1, 0,0,0);
                ub1 = __builtin_amdgcn_mfma_f32_16x16x32_bf16(
                        __builtin_bit_cast(bf16x8, dv1), __builtin_bit_cast(bf16x8, f1), ub1, 0,0,0);
            }
        }
        // counted drain: need stage cl+1 done; stage cl+2 (6 loads) may stay in flight
        if (cl + 2 < NCH / 2) asm volatile("s_waitcnt vmcnt(6) lgkmcnt(0)" ::: "memory");
        else                  asm volatile("s_waitcnt vmcnt(0) lgkmcnt(0)" ::: "memory");
        __builtin_amdgcn_s_barrier();
    }

    // epilogue: combine s-halves, write partial A tiles + u for both batches
    float* red0 = (float*)&gbuf[0][0];     // 12 KB used
    float* red1 = (float*)&gbuf[1][0];
    if (w < 6 && half == 0) {
#pragma unroll
        for (int g = 0; g < 16; ++g) {
            int row = (g & 3) + 8*(g >> 2) + 4*hsel;          // 32x32 C/D layout (m74/m101)
            red0[tilid*1024 + row*32 + l31] = acc0[g];
            red1[tilid*1024 + row*32 + l31] = acc1[g];
        }
    }
    if (w >= 6 && lane < 16) {                                 // 16x16 D row0 = u
        const int cb0 = (w == 6) ? 0 : 32;
        float* U0 = Upart + ((size_t)nhalf * BBV + b0) * KKV;
        float* U1 = Upart + ((size_t)nhalf * BBV + b1) * KKV;
        U0[cb0 + lane]      = ua0[0];
        U0[cb0 + 16 + lane] = ub0[0];
        U1[cb0 + lane]      = ua1[0];
        U1[cb0 + 16 + lane] = ub1[0];
    }
    __syncthreads();
    if (w < 6 && half == 1) {
        float* A0 = Apart + ((size_t)nhalf * BBV + b0) * 4096;
        float* A1 = Apart + ((size_t)nhalf * BBV + b1) * 4096;
#pragma unroll
        for (int g = 0; g < 16; ++g) {
            int row = (g & 3) + 8*(g >> 2) + 4*hsel;
            int gr = (tilid == 0) ? row : 32 + row;
            int gc = (tilid == 2) ? 32 + l31 : l31;
            A0[gr*64 + gc] = red0[tilid*1024 + row*32 + l31] + acc0[g];
            A1[gr*64 + gc] = red1[tilid*1024 + row*32 + l31] + acc1[g];
        }
    }
#undef STAGE
}

// ======= K3: register-resident Cholesky + solve, 8 batches (waves) per block =======
// 32 blocks x 512 threads -> 8 waves/CU = 2 waves/SIMD: readlane->fma dependency
// stalls of one wave are hidden by its SIMD co-resident wave (R7 ran 1 wave/CU,
// fully latency-exposed). All indices compile-time static (rule #20).
__global__ __launch_bounds__(512, 2) void chol64(
    const float* __restrict__ Apart, const float* __restrict__ Upart,
    const float* __restrict__ scal, float* __restrict__ out) {
    const int b = blockIdx.x * 8 + (threadIdx.x >> 6);   // batch per wave
    const int lane = threadIdx.x & 63;
    const float* Ar0 = Apart + (size_t)b * 4096 + lane * 64;
    const float* Ar1 = Apart + ((size_t)BBV + b) * 4096 + lane * 64;

    // In-place: Lrow[j] starts as A[lane][j] (two n-half partials summed),
    // gets overwritten with L column j at iteration j.
    float Lrow[64];
#pragma unroll
    for (int j4 = 0; j4 < 16; ++j4) {
        float4 v0 = *(const float4*)(Ar0 + j4 * 4);
        float4 v1 = *(const float4*)(Ar1 + j4 * 4);
        Lrow[j4*4+0] = v0.x + v1.x;
        Lrow[j4*4+1] = v0.y + v1.y;
        Lrow[j4*4+2] = v0.z + v1.z;
        Lrow[j4*4+3] = v0.w + v1.w;
    }
    float ubr = Upart[b * 64 + lane] + Upart[(BBV + b) * 64 + lane];

    float dval = 1.f, invd = 0.f;
#pragma unroll
    for (int j = 0; j < 64; ++j) {
        float sacc[4] = {0.f, 0.f, 0.f, 0.f};   // 4-way chain split, static idx (k literal)
#pragma unroll
        for (int k = 0; k < j; ++k)
            sacc[k & 3] += Lrow[k] * rlane(Lrow[k], j);   // L[j][k] broadcast
        float a = Lrow[j] + ((lane == j) ? 1.0f : 0.0f)
                - ((sacc[0] + sacc[1]) + (sacc[2] + sacc[3]));
        float dv = rlane(a, j);                 // = Ljj^2 (lane j's value)
        float invs = rsqrtf(dv);
        if (lane == j) { dval = dv; invd = invs; }
        Lrow[j] = (lane > j) ? a * invs : 0.f;  // strict lower col j (diag excluded)
    }

    // forward solve L z = u ; z2 = ||z||^2 (wave-uniform via readlanes)
    float z2 = 0.f;
#pragma unroll
    for (int j = 0; j < 64; ++j) {
        float zj = rlane(ubr, j) * rlane(invd, j);
        z2 += zj * zj;
        ubr -= Lrow[j] * zj;                    // Lrow[j]=0 for lane<=j
    }

    // logdetA = sum_j log(Ljj^2): one log per lane + butterfly
    float ld = __logf(dval);
#pragma unroll
    for (int off = 32; off > 0; off >>= 1) ld += __shfl_xor(ld, off);

    if (lane == 0) {
        float uni = scal[b*5+0], wdd = scal[b*5+1], nb = scal[b*5+2],
              mlp = scal[b*5+3], extra = scal[b*5+4];
        const float LOG2PI = 1.8378770664093453f;
        out[b] = uni + extra - 0.5f * (nb * LOG2PI + mlp + ld + (wdd - z2));
    }
}

extern "C" void kernel_launch(void* const* d_in, const int* in_sizes, int n_in,
                              void* d_out, int out_size, void* d_ws, size_t ws_size,
                              hipStream_t stream) {
    const float* targets = (const float*)d_in[0];
    const float* rho     = (const float*)d_in[1];
    const float* qs      = (const float*)d_in[2];
    const float* means   = (const float*)d_in[3];
    const float* C       = (const float*)d_in[4];
    const float* psi     = (const float*)d_in[5];
    float* out = (float*)d_out;

    char* ws = (char*)d_ws;
    u16* Csbf   = (u16*)(ws);                                     // 512 KB
    u16* dsbf   = (u16*)(ws + 0x80000);                           // 2 MB
    u32* mask2  = (u32*)(ws + 0x280000);                          // 2 MB
    float* Apart = (float*)(ws + 0x480000);                       // 8 MB (2 n-halves)
    float* Upart = (float*)(ws + 0xC80000);                       // 128 KB (2 n-halves)
    float* scal  = (float*)(ws + 0xCC0000);                       // 5 KB

    prep<<<BBV + KKV, 256, 0, stream>>>(targets, rho, qs, means, C, psi,
                                        Csbf, dsbf, mask2, scal);
    gram<<<BBV, 512, 0, stream>>>(Csbf, dsbf, mask2, Apart, Upart);
    chol64<<<BBV / 8, 512, 0, stream>>>(Apart, Upart, scal, out);
}

// Round 9
// 46.071 us; speedup vs baseline: 1.2615x; 1.2615x over previous
//
#include <hip/hip_runtime.h>
#include <math.h>

#define NNV 4096   // N
#define KKV 64     // K
#define BBV 256    // B
#define CHN 256    // n-chunk staged in LDS
#define NCH (NNV / CHN)

typedef unsigned short u16;
typedef unsigned int u32;
typedef u32  u32x4  __attribute__((ext_vector_type(4)));
typedef short bf16x8 __attribute__((ext_vector_type(8)));
typedef float f32x4  __attribute__((ext_vector_type(4)));
typedef float f32x16 __attribute__((ext_vector_type(16)));

__device__ inline u16 f2bf(float x) {           // RNE f32 -> bf16
    u32 u = __float_as_uint(x);
    u = u + 0x7FFFu + ((u >> 16) & 1u);
    return (u16)(u >> 16);
}

__device__ inline float rlane(float v, int l) { // wave-uniform readlane broadcast
    return __uint_as_float(__builtin_amdgcn_readlane(__float_as_uint(v), l));
}

// ================= K1: elementwise prep (+ Cs build in blocks 256..319) ===========
// Coalesced: pass i, thread t handles float4 at flat index i*1024 + t*4
// (lane-contiguous 16B; R8 and earlier used t*16 -> stride-64B, 4x transactions).
__global__ __launch_bounds__(256) void prep(
    const float* __restrict__ targets, const float* __restrict__ rho,
    const float* __restrict__ qs, const float* __restrict__ means,
    const float* __restrict__ C, const float* __restrict__ psi,
    u16* __restrict__ Csbf, u16* __restrict__ dsbf,
    u32* __restrict__ mask2, float* __restrict__ scal) {
    const int blk = blockIdx.x;
    const int t = threadIdx.x;

    if (blk >= BBV) {                    // Cs = C * rsqrt(psi), bf16, row-major [64][4096]
        const int k = blk - BBV;
        const float* Crow = C + (size_t)k * NNV;
        u16* Orow = Csbf + (size_t)k * NNV;
#pragma unroll
        for (int i = 0; i < 4; ++i) {
            int n4 = i * 1024 + t * 4;
            float4 cv = *(const float4*)(Crow + n4);
            float4 pv = *(const float4*)(psi + n4);
            u32 w0 = (u32)f2bf(cv.x * rsqrtf(pv.x)) | ((u32)f2bf(cv.y * rsqrtf(pv.y)) << 16);
            u32 w1 = (u32)f2bf(cv.z * rsqrtf(pv.z)) | ((u32)f2bf(cv.w * rsqrtf(pv.w)) << 16);
            *(uint2*)(Orow + n4) = make_uint2(w0, w1);
        }
        return;
    }

    __shared__ float sred[4][5];
    const int b = blk;
    const int lane = t & 63, wid = t >> 6;
    const float rho_s = rho[0];
    const float lrho = __logf(rho_s);
    const float* tg = targets + (size_t)b * NNV;
    const float* qb = qs + (size_t)b * NNV;
    const float* mb = means + (size_t)b * NNV;

    float s_uni = 0.f, s_wdd = 0.f, s_nb = 0.f, s_mlp = 0.f, s_extra = 0.f;
#pragma unroll
    for (int i = 0; i < 4; ++i) {
        int n4 = i * 1024 + t * 4;
        float4 tv4 = *(const float4*)(tg + n4);
        float4 qv4 = *(const float4*)(qb + n4);
        float4 mu4 = *(const float4*)(mb + n4);
        float4 pv4 = *(const float4*)(psi + n4);
        float tvv[4] = {tv4.x, tv4.y, tv4.z, tv4.w};
        float qv [4] = {qv4.x, qv4.y, qv4.z, qv4.w};
        float muv[4] = {mu4.x, mu4.y, mu4.z, mu4.w};
        float pv [4] = {pv4.x, pv4.y, pv4.z, pv4.w};
        u16 dsv[4]; bool mk[4];
#pragma unroll
        for (int j = 0; j < 4; ++j) {
            bool m = tvv[j] >= rho_s;
            float ds = 0.f;
            if (m) {
                float y = __logf(tvv[j]);
                float d = y - muv[j];
                ds = d * rsqrtf(pv[j]);               // ds^2 = w*d^2
                s_wdd += ds * ds;
                s_nb += 1.f;
                s_mlp += __logf(pv[j]);
                s_extra += __logf(qv[j]) - y;
            } else {
                s_uni += __logf(1.f - qv[j]) - lrho;
            }
            dsv[j] = f2bf(ds);
            mk[j] = m;
        }
        u32 d0 = (u32)dsv[0] | ((u32)dsv[1] << 16);
        u32 d1 = (u32)dsv[2] | ((u32)dsv[3] << 16);
        u32 m0 = (mk[0] ? 0xFFFFu : 0u) | (mk[1] ? 0xFFFF0000u : 0u);
        u32 m1 = (mk[2] ? 0xFFFFu : 0u) | (mk[3] ? 0xFFFF0000u : 0u);
        *(uint2*)(dsbf + (size_t)b * NNV + n4) = make_uint2(d0, d1);
        *(uint2*)(mask2 + (size_t)b * (NNV/2) + n4/2) = make_uint2(m0, m1);
    }

#pragma unroll
    for (int off = 32; off > 0; off >>= 1) {
        s_uni  += __shfl_down(s_uni, off);
        s_wdd  += __shfl_down(s_wdd, off);
        s_nb   += __shfl_down(s_nb, off);
        s_mlp  += __shfl_down(s_mlp, off);
        s_extra+= __shfl_down(s_extra, off);
    }
    if (lane == 0) {
        sred[wid][0] = s_uni; sred[wid][1] = s_wdd; sred[wid][2] = s_nb;
        sred[wid][3] = s_mlp; sred[wid][4] = s_extra;
    }
    __syncthreads();
    if (t == 0) {
        float a0=0,a1=0,a2=0,a3=0,a4=0;
#pragma unroll
        for (int w4 = 0; w4 < 4; ++w4) {
            a0 += sred[w4][0]; a1 += sred[w4][1]; a2 += sred[w4][2];
            a3 += sred[w4][3]; a4 += sred[w4][4];
        }
        scal[b*5+0]=a0; scal[b*5+1]=a1; scal[b*5+2]=a2; scal[b*5+3]=a3; scal[b*5+4]=a4;
    }
}

// ========== K2: Gram via MFMA — 2 batches/block share Cs reads, n-split in 2 ==========
// Block (pair,nhalf) processes batches {2*pair, 2*pair+1} over n in [nhalf*2048, ...+2048).
// Writes partial A, u; chol64 sums the two n-half partials.
__global__ __launch_bounds__(512, 2) void gram(
    const u16* __restrict__ Csbf, const u16* __restrict__ dsbf,
    const u32* __restrict__ mask2g, float* __restrict__ Apart, float* __restrict__ Upart) {
    __shared__ __align__(16) u16 gbuf[3][KKV * CHN];   // swizzled Cs chunk, 32 KB each
    __shared__ __align__(16) u16 dsrow[2][3][512];     // per-batch ds rows (upper 512B dup)
    __shared__ __align__(16) u32 m2[2][NNV / 2];       // per-batch packed masks, 8 KB each

    const int bid = blockIdx.x;
    const int nhalf = bid & 1;
    const int pair = bid >> 1;
    const int b0 = pair * 2, b1 = b0 + 1;
    const int c0 = nhalf * (NCH / 2);    // first chunk of this block's n-range

    const int t = threadIdx.x;
    const int lane = t & 63;
    const int w = t >> 6;
    const int half = w & 1;
    const int tilid = w >> 1;          // 0,1,2 = A00,A10,A11 ; 3 = u-waves
    const int l31 = lane & 31;
    const int hsel = lane >> 5;

    {   // stage both batches' mask words (full 8 KB each; only our half is read)
        u32x4 v0 = *(const u32x4*)(mask2g + (size_t)b0 * (NNV/2) + t*4);
        *(u32x4*)(&m2[0][t*4]) = v0;
        u32x4 v1 = *(const u32x4*)(mask2g + (size_t)b1 * (NNV/2) + t*4);
        *(u32x4*)(&m2[1][t*4]) = v1;
    }

    f32x16 acc0, acc1;
#pragma unroll
    for (int i = 0; i < 16; ++i) { acc0[i] = 0.f; acc1[i] = 0.f; }
    f32x4 ua0, ub0, ua1, ub1;
#pragma unroll
    for (int i = 0; i < 4; ++i) { ua0[i] = 0.f; ub0[i] = 0.f; ua1[i] = 0.f; ub1[i] = 0.f; }

// Every wave issues exactly 6 global_load_lds per STAGE (4 Cs rows + 2 ds-rows;
// ds-rows written identically by all 8 waves -> benign, keeps vmcnt uniform).
#define STAGE(cc, pp) do {                                                          \
    _Pragma("unroll")                                                               \
    for (int i_ = 0; i_ < 4; ++i_) {                                                \
        int beta0 = w*256 + i_*64;                                                  \
        int beta = beta0 + lane;                                                    \
        int r_ = beta >> 5, blkP = beta & 31;                                       \
        int blkS = blkP ^ (r_ & 15);   /* source pre-swizzle (m173 pattern) */      \
        const u16* src = Csbf + (size_t)r_ * NNV + (cc)*CHN + blkS*8;               \
        __builtin_amdgcn_global_load_lds(                                           \
            (const __attribute__((address_space(1))) void*)src,                     \
            (__attribute__((address_space(3))) void*)(&gbuf[pp][beta0*8]),          \
            16, 0, 0);                                                              \
    }                                                                               \
    {                                                                               \
        const u16* s0_ = dsbf + (size_t)b0 * NNV + (cc)*CHN + (lane & 31)*8;        \
        __builtin_amdgcn_global_load_lds(                                           \
            (const __attribute__((address_space(1))) void*)s0_,                     \
            (__attribute__((address_space(3))) void*)(&dsrow[0][pp][0]),            \
            16, 0, 0);                                                              \
        const u16* s1_ = dsbf + (size_t)b1 * NNV + (cc)*CHN + (lane & 31)*8;        \
        __builtin_amdgcn_global_load_lds(                                           \
            (const __attribute__((address_space(1))) void*)s1_,                     \
            (__attribute__((address_space(3))) void*)(&dsrow[1][pp][0]),            \
            16, 0, 0);                                                              \
    }                                                                               \
} while (0)

    STAGE(c0 + 0, 0);
    STAGE(c0 + 1, 1);
    // wait stage-0 complete (stage-1's 6 loads may remain in flight) + m2 writes
    asm volatile("s_waitcnt vmcnt(6) lgkmcnt(0)" ::: "memory");
    __builtin_amdgcn_s_barrier();

#pragma unroll
    for (int cl = 0; cl < NCH / 2; ++cl) {
        const int c = c0 + cl;
        const int p = cl % 3;
        if (cl + 2 < NCH / 2) STAGE(c0 + cl + 2, (cl + 2) % 3);
        const char* gb = (const char*)gbuf[p];
        if (w < 6) {
            const int rbA = (tilid == 0) ? 0 : 32;
            const int rbB = (tilid == 2) ? 32 : 0;
            const int rA = rbA + l31, rB = rbB + l31;
            const int swA = (rA & 15) << 4, swB = (rB & 15) << 4;
            const char* mb0 = (const char*)&m2[0][0] + c*512 + hsel*16;
            const char* mb1 = (const char*)&m2[1][0] + c*512 + hsel*16;
#pragma unroll
            for (int s8 = 0; s8 < 8; ++s8) {
                const int s = half*8 + s8;
                const int colbyte = s*32 + hsel*16;
                u32x4 fB = *(const u32x4*)(gb + rB*512 + (colbyte ^ swB));
                u32x4 fAr;
                if (tilid == 1) fAr = *(const u32x4*)(gb + rA*512 + (colbyte ^ swA));
                else            fAr = fB;                      // diag tiles: reuse read
                u32x4 mk0 = *(const u32x4*)(mb0 + s*32);       // broadcast per half-wave
                u32x4 mk1 = *(const u32x4*)(mb1 + s*32);
                u32x4 fA0 = fAr & mk0;                         // mask A-side only (m^2=m)
                u32x4 fA1 = fAr & mk1;
                acc0 = __builtin_amdgcn_mfma_f32_32x32x16_bf16(
                        __builtin_bit_cast(bf16x8, fA0),
                        __builtin_bit_cast(bf16x8, fB), acc0, 0, 0, 0);
                acc1 = __builtin_amdgcn_mfma_f32_32x32x16_bf16(
                        __builtin_bit_cast(bf16x8, fA1),
                        __builtin_bit_cast(bf16x8, fB), acc1, 0, 0, 0);
            }
        } else {
            const int cb0 = (w == 6) ? 0 : 32;
            const int l15 = lane & 15;
            const int g4 = lane >> 4;
            const int r0 = cb0 + l15, r1 = r0 + 16;
            const int sw0 = (r0 & 15) << 4, sw1 = (r1 & 15) << 4;
            const char* dr0 = (const char*)&dsrow[0][p][0];
            const char* dr1 = (const char*)&dsrow[1][p][0];
#pragma unroll
            for (int su = 0; su < 8; ++su) {
                const int colbyte = su*64 + g4*16;
                u32x4 dv0 = *(const u32x4*)(dr0 + colbyte);    // broadcast
                u32x4 dv1 = *(const u32x4*)(dr1 + colbyte);
                if (l15 != 0) { dv0 = dv0 ^ dv0; dv1 = dv1 ^ dv1; }  // A rows 1..15 = 0
                u32x4 f0 = *(const u32x4*)(gb + r0*512 + (colbyte ^ sw0));
                u32x4 f1 = *(const u32x4*)(gb + r1*512 + (colbyte ^ sw1));
                ua0 = __builtin_amdgcn_mfma_f32_16x16x32_bf16(
                        __builtin_bit_cast(bf16x8, dv0), __builtin_bit_cast(bf16x8, f0), ua0, 0,0,0);
                ub0 = __builtin_amdgcn_mfma_f32_16x16x32_bf16(
                        __builtin_bit_cast(bf16x8, dv0), __builtin_bit_cast(bf16x8, f1), ub0, 0,0,0);
                ua1 = __builtin_amdgcn_mfma_f32_16x16x32_bf16(
                        __builtin_bit_cast(bf16x8, dv1), __builtin_bit_cast(bf16x8, f0), ua1, 0,0,0);
                ub1 = __builtin_amdgcn_mfma_f32_16x16x32_bf16(
                        __builtin_bit_cast(bf16x8, dv1), __builtin_bit_cast(bf16x8, f1), ub1, 0,0,0);
            }
        }
        // counted drain: need stage cl+1 done; stage cl+2 (6 loads) may stay in flight
        if (cl + 2 < NCH / 2) asm volatile("s_waitcnt vmcnt(6) lgkmcnt(0)" ::: "memory");
        else                  asm volatile("s_waitcnt vmcnt(0) lgkmcnt(0)" ::: "memory");
        __builtin_amdgcn_s_barrier();
    }

    // epilogue: combine s-halves, write partial A tiles + u for both batches
    float* red0 = (float*)&gbuf[0][0];     // 12 KB used
    float* red1 = (float*)&gbuf[1][0];
    if (w < 6 && half == 0) {
#pragma unroll
        for (int g = 0; g < 16; ++g) {
            int row = (g & 3) + 8*(g >> 2) + 4*hsel;          // 32x32 C/D layout (m74/m101)
            red0[tilid*1024 + row*32 + l31] = acc0[g];
            red1[tilid*1024 + row*32 + l31] = acc1[g];
        }
    }
    if (w >= 6 && lane < 16) {                                 // 16x16 D row0 = u
        const int cb0 = (w == 6) ? 0 : 32;
        float* U0 = Upart + ((size_t)nhalf * BBV + b0) * KKV;
        float* U1 = Upart + ((size_t)nhalf * BBV + b1) * KKV;
        U0[cb0 + lane]      = ua0[0];
        U0[cb0 + 16 + lane] = ub0[0];
        U1[cb0 + lane]      = ua1[0];
        U1[cb0 + 16 + lane] = ub1[0];
    }
    __syncthreads();
    if (w < 6 && half == 1) {
        float* A0 = Apart + ((size_t)nhalf * BBV + b0) * 4096;
        float* A1 = Apart + ((size_t)nhalf * BBV + b1) * 4096;
#pragma unroll
        for (int g = 0; g < 16; ++g) {
            int row = (g & 3) + 8*(g >> 2) + 4*hsel;
            int gr = (tilid == 0) ? row : 32 + row;
            int gc = (tilid == 2) ? 32 + l31 : l31;
            A0[gr*64 + gc] = red0[tilid*1024 + row*32 + l31] + acc0[g];
            A1[gr*64 + gc] = red1[tilid*1024 + row*32 + l31] + acc1[g];
        }
    }
#undef STAGE
}

// ======= K3: single-wave register-resident Cholesky + solve + assembly =======
// R7-proven config: 1 wave/block, launch_bounds(64,1) -> full 512-VGPR budget,
// no spill (R8's (512,2) packing capped VGPR at 256 and regressed +12us).
__global__ __launch_bounds__(64, 1) void chol64(
    const float* __restrict__ Apart, const float* __restrict__ Upart,
    const float* __restrict__ scal, float* __restrict__ out) {
    const int b = blockIdx.x;
    const int lane = threadIdx.x;          // 0..63
    const float* Ar0 = Apart + (size_t)b * 4096 + lane * 64;
    const float* Ar1 = Apart + ((size_t)BBV + b) * 4096 + lane * 64;

    // In-place: Lrow[j] starts as A[lane][j] (two n-half partials summed),
    // gets overwritten with L column j at iteration j.
    float Lrow[64];
#pragma unroll
    for (int j4 = 0; j4 < 16; ++j4) {
        float4 v0 = *(const float4*)(Ar0 + j4 * 4);
        float4 v1 = *(const float4*)(Ar1 + j4 * 4);
        Lrow[j4*4+0] = v0.x + v1.x;
        Lrow[j4*4+1] = v0.y + v1.y;
        Lrow[j4*4+2] = v0.z + v1.z;
        Lrow[j4*4+3] = v0.w + v1.w;
    }
    float ubr = Upart[b * 64 + lane] + Upart[(BBV + b) * 64 + lane];

    float dval = 1.f, invd = 0.f;
#pragma unroll
    for (int j = 0; j < 64; ++j) {
        float sacc[4] = {0.f, 0.f, 0.f, 0.f};   // 4-way chain split, static idx (k literal)
#pragma unroll
        for (int k = 0; k < j; ++k)
            sacc[k & 3] += Lrow[k] * rlane(Lrow[k], j);   // L[j][k] broadcast
        float a = Lrow[j] + ((lane == j) ? 1.0f : 0.0f)
                - ((sacc[0] + sacc[1]) + (sacc[2] + sacc[3]));
        float dv = rlane(a, j);                 // = Ljj^2 (lane j's value)
        float invs = rsqrtf(dv);
        if (lane == j) { dval = dv; invd = invs; }
        Lrow[j] = (lane > j) ? a * invs : 0.f;  // strict lower col j (diag excluded)
    }

    // forward solve L z = u ; z2 = ||z||^2 (wave-uniform via readlanes)
    float z2 = 0.f;
#pragma unroll
    for (int j = 0; j < 64; ++j) {
        float zj = rlane(ubr, j) * rlane(invd, j);
        z2 += zj * zj;
        ubr -= Lrow[j] * zj;                    // Lrow[j]=0 for lane<=j
    }

    // logdetA = sum_j log(Ljj^2): one log per lane + butterfly
    float ld = __logf(dval);
#pragma unroll
    for (int off = 32; off > 0; off >>= 1) ld += __shfl_xor(ld, off);

    if (lane == 0) {
        float uni = scal[b*5+0], wdd = scal[b*5+1], nb = scal[b*5+2],
              mlp = scal[b*5+3], extra = scal[b*5+4];
        const float LOG2PI = 1.8378770664093453f;
        out[b] = uni + extra - 0.5f * (nb * LOG2PI + mlp + ld + (wdd - z2));
    }
}

extern "C" void kernel_launch(void* const* d_in, const int* in_sizes, int n_in,
                              void* d_out, int out_size, void* d_ws, size_t ws_size,
                              hipStream_t stream) {
    const float* targets = (const float*)d_in[0];
    const float* rho     = (const float*)d_in[1];
    const float* qs      = (const float*)d_in[2];
    const float* means   = (const float*)d_in[3];
    const float* C       = (const float*)d_in[4];
    const float* psi     = (const float*)d_in[5];
    float* out = (float*)d_out;

    char* ws = (char*)d_ws;
    u16* Csbf   = (u16*)(ws);                                     // 512 KB
    u16* dsbf   = (u16*)(ws + 0x80000);                           // 2 MB
    u32* mask2  = (u32*)(ws + 0x280000);                          // 2 MB
    float* Apart = (float*)(ws + 0x480000);                       // 8 MB (2 n-halves)
    float* Upart = (float*)(ws + 0xC80000);                       // 128 KB (2 n-halves)
    float* scal  = (float*)(ws + 0xCC0000);                       // 5 KB

    prep<<<BBV + KKV, 256, 0, stream>>>(targets, rho, qs, means, C, psi,
                                        Csbf, dsbf, mask2, scal);
    gram<<<BBV, 512, 0, stream>>>(Csbf, dsbf, mask2, Apart, Upart);
    chol64<<<BBV, 64, 0, stream>>>(Apart, Upart, scal, out);
}